// Round 2
// baseline (5940.789 us; speedup 1.0000x reference)
//
#include <hip/hip_runtime.h>

typedef unsigned short u16;
typedef short bf16x8 __attribute__((ext_vector_type(8)));
typedef float f32x4 __attribute__((ext_vector_type(4)));
typedef u16 u16x4 __attribute__((ext_vector_type(4)));

#define DEV __device__ __forceinline__

#define NB 16
#define SEQ 197
#define DIM 768
#define MROWS (NB * SEQ)      // 3152
#define NPATCH 196
#define PROWS (NB * NPATCH)   // 3136
#define MLPD 3072
#define NHEAD 12

DEV u16 f2bf(float f) {
  union { float f; unsigned u; } c; c.f = f;
  return (u16)((c.u + 0x7FFFu + ((c.u >> 16) & 1u)) >> 16);
}

DEV void async_ld16(const void* g, void* l) {
  __builtin_amdgcn_global_load_lds(
      (__attribute__((address_space(1))) unsigned int*)(g),
      (__attribute__((address_space(3))) unsigned int*)(l), 16, 0, 0);
}

// ---------------- weight conversion (f32 -> bf16), vectorized x4 ----------------
// Generic: dst[layer*dstride + off + rem] = bf16(src[i]); plain convert = (npl4=n4, dstride=0, off=0)
__global__ void k_cvt_off4(const float* __restrict__ src, u16* __restrict__ dst,
                           long npl4, long dstride, long off, long n4) {
  long i = (long)blockIdx.x * 256 + threadIdx.x;
  long st = (long)gridDim.x * 256;
  for (; i < n4; i += st) {
    long layer = i / npl4, rem = i - layer * npl4;
    f32x4 v = *(const f32x4*)(src + i * 4);
    u16x4 o;
    #pragma unroll
    for (int j = 0; j < 4; ++j) o[j] = f2bf(v[j]);
    *(u16x4*)(dst + layer * dstride + off + rem * 4) = o;
  }
}

// dtproj_w (12,768,48) -> (12,768,64) bf16, zero-padded cols 48..63
__global__ void k_cvt_dtw4(const float* __restrict__ src, u16* __restrict__ dst) {
  long i = (long)blockIdx.x * 256 + threadIdx.x;  // over 12*768*16 groups of 4
  if (i >= 12L * 768 * 16) return;
  long e = i * 4;
  long col = e & 63, row = e >> 6;
  u16x4 o;
  if (col < 48) {
    f32x4 v = *(const f32x4*)(src + row * 48 + col);
    #pragma unroll
    for (int j = 0; j < 4; ++j) o[j] = f2bf(v[j]);
  } else {
    o[0] = o[1] = o[2] = o[3] = 0;
  }
  *(u16x4*)(dst + e) = o;
}

// ---------------- patch embed ----------------
__global__ void k_patch_gather(const float* __restrict__ x, u16* __restrict__ Xp) {
  long i = (long)blockIdx.x * 256 + threadIdx.x;  // 3136*192
  if (i >= (long)PROWS * 192) return;
  int kk = (int)(i % 192) * 4;
  long m = i / 192;
  int bb = (int)(m / NPATCH), t = (int)(m % NPATCH);
  int ph = t / 14, pw = t - ph * 14;
  int c = kk >> 8, py = (kk >> 4) & 15, px = kk & 15;
  const float* sp = x + (((long)bb * 3 + c) * 224 + ph * 16 + py) * 224 + pw * 16 + px;
  f32x4 v = *(const f32x4*)sp;
  u16x4 o;
  #pragma unroll
  for (int j = 0; j < 4; ++j) o[j] = f2bf(v[j]);
  *(u16x4*)(Xp + m * DIM + kk) = o;
}

__global__ void k_assemble(const float* __restrict__ peout, const float* __restrict__ pos,
                           const float* __restrict__ cls, float* __restrict__ tok) {
  long i = (long)blockIdx.x * 256 + threadIdx.x;  // 3152*192
  if (i >= (long)MROWS * 192) return;
  int d4 = (int)(i % 192) * 4;
  long m = i / 192;
  int l = (int)(m % SEQ);
  long bb = m / SEQ;
  f32x4 v;
  if (l == 0) {
    v = *(const f32x4*)(cls + d4);
  } else {
    long pm = bb * NPATCH + (l - 1);
    f32x4 a = *(const f32x4*)(peout + pm * DIM + d4);
    f32x4 pz = *(const f32x4*)(pos + (long)(l - 1) * DIM + d4);
    v = a + pz;
  }
  *(f32x4*)(tok + m * DIM + d4) = v;
}

// ---------------- layernorm (D=768, block=256, 3 elems/thread) ----------------
__global__ __launch_bounds__(256) void k_layernorm(
    const float* __restrict__ x, long rstride,
    const float* __restrict__ w, const float* __restrict__ bb,
    float* __restrict__ outf, u16* __restrict__ outbf, long ostride) {
  __shared__ float red[8];
  int row = blockIdx.x, tid = threadIdx.x;
  const float* xr = x + (long)row * rstride;
  float v0 = xr[tid], v1 = xr[tid + 256], v2 = xr[tid + 512];
  float s = v0 + v1 + v2, s2 = v0 * v0 + v1 * v1 + v2 * v2;
  #pragma unroll
  for (int m = 1; m < 64; m <<= 1) { s += __shfl_xor(s, m, 64); s2 += __shfl_xor(s2, m, 64); }
  if ((tid & 63) == 0) { red[(tid >> 6) * 2] = s; red[(tid >> 6) * 2 + 1] = s2; }
  __syncthreads();
  s = red[0] + red[2] + red[4] + red[6];
  s2 = red[1] + red[3] + red[5] + red[7];
  float mean = s * (1.f / 768.f);
  float var = s2 * (1.f / 768.f) - mean * mean;
  float rstd = rsqrtf(var + 1e-5f);
  float* of = outf ? outf + (long)row * ostride : nullptr;
  u16* ob = outbf ? outbf + (long)row * ostride : nullptr;
  int d = tid;
  #pragma unroll
  for (int j = 0; j < 3; ++j, d += 256) {
    float val = (j == 0) ? v0 : ((j == 1) ? v1 : v2);
    float y = (val - mean) * rstd * w[d] + bb[d];
    if (of) of[d] = y;
    if (ob) ob[d] = f2bf(y);
  }
}

// ---------------- causal depthwise conv (K=4, left pad 3) ----------------
__global__ void k_conv(const float* __restrict__ xn, const float* __restrict__ cw,
                       const float* __restrict__ cb, float* __restrict__ xc,
                       u16* __restrict__ xcbf) {
  long gid = (long)blockIdx.x * 256 + threadIdx.x;
  if (gid >= (long)MROWS * DIM) return;
  int d = (int)(gid % DIM);
  long m = gid / DIM;
  int l = (int)(m % SEQ);
  long b = m / SEQ;
  const float* w4 = cw + (long)d * 4;
  float a = cb[d];
  #pragma unroll
  for (int k = 0; k < 4; ++k) {
    int ls = l - 3 + k;
    if (ls >= 0) a += w4[k] * xn[(b * SEQ + ls) * DIM + d];
  }
  xc[gid] = a;
  xcbf[gid] = f2bf(a);
}

// ---------------- split x_dbl (3152x80) -> dtpad bf16 (x64), Bm, Cm f32 (x16) ----------------
__global__ void k_split(const float* __restrict__ xdbl, u16* __restrict__ dtpad,
                        float* __restrict__ Bm, float* __restrict__ Cm) {
  long gid = (long)blockIdx.x * 256 + threadIdx.x;
  if (gid >= (long)MROWS * 96) return;
  int j = (int)(gid % 96);
  long m = gid / 96;
  const float* xr = xdbl + m * 80;
  if (j < 64) dtpad[m * 64 + j] = (j < 48) ? f2bf(xr[j]) : (u16)0;
  else if (j < 80) Bm[m * 16 + (j - 64)] = xr[j - 16];
  else Cm[m * 16 + (j - 80)] = xr[j - 16];
}

// ---------------- selective scan: thread = (b, d, 4-state group) ----------------
__global__ __launch_bounds__(256) void k_scan(
    const float* __restrict__ dtraw, const float* __restrict__ xc,
    const float* __restrict__ Bm, const float* __restrict__ Cm,
    const float* __restrict__ Alog, const float* __restrict__ dtb,
    const float* __restrict__ Dpr, float* __restrict__ ssmy) {
  int gid = blockIdx.x * 256 + threadIdx.x;  // 16*768*4 = 49152
  int ng = gid & 3;
  int rest = gid >> 2;
  int d = rest % DIM;
  int b = rest / DIM;
  float a0 = -__expf(Alog[d * 16 + ng * 4 + 0]);
  float a1 = -__expf(Alog[d * 16 + ng * 4 + 1]);
  float a2 = -__expf(Alog[d * 16 + ng * 4 + 2]);
  float a3 = -__expf(Alog[d * 16 + ng * 4 + 3]);
  float bt = dtb[d], Dv = Dpr[d];
  float h0 = 0.f, h1 = 0.f, h2 = 0.f, h3 = 0.f;
  for (int l = 0; l < SEQ; ++l) {
    long base = (long)b * SEQ + l;
    float dtr = dtraw[base * DIM + d] + bt;
    float dt = dtr > 20.f ? dtr : log1pf(__expf(dtr));  // softplus
    float xcv = xc[base * DIM + d];
    f32x4 Bv = *(const f32x4*)(Bm + base * 16 + ng * 4);
    f32x4 Cv = *(const f32x4*)(Cm + base * 16 + ng * 4);
    float dtx = dt * xcv;
    h0 = __expf(dt * a0) * h0 + dtx * Bv[0];
    h1 = __expf(dt * a1) * h1 + dtx * Bv[1];
    h2 = __expf(dt * a2) * h2 + dtx * Bv[2];
    h3 = __expf(dt * a3) * h3 + dtx * Bv[3];
    float y = h0 * Cv[0] + h1 * Cv[1] + h2 * Cv[2] + h3 * Cv[3];
    y += __shfl_xor(y, 1, 64);
    y += __shfl_xor(y, 2, 64);
    if (ng == 0) ssmy[base * DIM + d] = y + xcv * Dv;
  }
}

// ---------------- GEMM: C[M,N] = A[M,K](bf16) @ W[N,K]^T(bf16), 128x128 tile ----------------
// MODE 0: f32 C=acc; 1: f32 C=acc+bias; 2: bf16 C=gelu(acc+bias); 3: bf16 C=acc; 4: f32 C=acc+bias+res
template <int MODE>
__global__ __launch_bounds__(256) void k_gemm(
    const u16* __restrict__ A, const u16* __restrict__ Bw, void* __restrict__ Cout,
    const float* __restrict__ bias, const float* __restrict__ res,
    int M, int N, int K, int lda, int ldb, int ldc) {
  __shared__ __attribute__((aligned(16))) u16 lA[128 * 32];
  __shared__ __attribute__((aligned(16))) u16 lB[128 * 32];
  const int tid = threadIdx.x;
  const int w = tid >> 6, lane = tid & 63;
  const int m0 = blockIdx.x * 128, n0 = blockIdx.y * 128;
  const int wr = (w >> 1) * 64, wc = (w & 1) * 64;
  const int lg = lane >> 4, li = lane & 15;

  f32x4 z4 = {0.f, 0.f, 0.f, 0.f};
  f32x4 acc[4][4];
  #pragma unroll
  for (int i = 0; i < 4; ++i)
    #pragma unroll
    for (int j = 0; j < 4; ++j) acc[i][j] = z4;

  const int srow = w * 16 + (lane >> 2);   // staging row (+ r*64)
  const int skcol = (lane & 3) * 8;        // staging k offset (elems)

  for (int k0 = 0; k0 < K; k0 += 32) {
    #pragma unroll
    for (int r = 0; r < 2; ++r) {
      int ra = m0 + srow + r * 64; if (ra > M - 1) ra = M - 1;
      async_ld16(A + (size_t)ra * lda + k0 + skcol, lA + (r * 4 + w) * 512);
      int rb = n0 + srow + r * 64; if (rb > N - 1) rb = N - 1;
      async_ld16(Bw + (size_t)rb * ldb + k0 + skcol, lB + (r * 4 + w) * 512);
    }
    __syncthreads();
    bf16x8 af[4], bfr[4];
    #pragma unroll
    for (int i = 0; i < 4; ++i)
      af[i] = *(const bf16x8*)(lA + (wr + i * 16 + li) * 32 + lg * 8);
    #pragma unroll
    for (int j = 0; j < 4; ++j)
      bfr[j] = *(const bf16x8*)(lB + (wc + j * 16 + li) * 32 + lg * 8);
    #pragma unroll
    for (int i = 0; i < 4; ++i)
      #pragma unroll
      for (int j = 0; j < 4; ++j)
        acc[i][j] = __builtin_amdgcn_mfma_f32_16x16x32_bf16(af[i], bfr[j], acc[i][j], 0, 0, 0);
    __syncthreads();
  }

  float* Cf = (float*)Cout;
  u16* Cb = (u16*)Cout;
  #pragma unroll
  for (int i = 0; i < 4; ++i) {
    #pragma unroll
    for (int j = 0; j < 4; ++j) {
      int ncol = n0 + wc + j * 16 + li;
      if (ncol >= N) continue;
      #pragma unroll
      for (int r = 0; r < 4; ++r) {
        int m = m0 + wr + i * 16 + lg * 4 + r;
        if (m >= M) continue;
        float v = acc[i][j][r];
        size_t idx = (size_t)m * ldc + ncol;
        if constexpr (MODE == 0) {
          Cf[idx] = v;
        } else if constexpr (MODE == 1) {
          Cf[idx] = v + bias[ncol];
        } else if constexpr (MODE == 2) {
          float t = v + bias[ncol];
          Cb[idx] = f2bf(0.5f * t * (1.f + erff(t * 0.70710678118f)));
        } else if constexpr (MODE == 3) {
          Cb[idx] = f2bf(v);
        } else {
          Cf[idx] = v + bias[ncol] + res[idx];
        }
      }
    }
  }
}

// ---------------- fused attention per (b,h): qkv bf16 (M x 2304) -> o bf16 (M x 768) ----------------
#define ALP 232  // padded k-stride for VT / P (2-way-ish LDS banks)
__global__ __launch_bounds__(256) void k_attn(const u16* __restrict__ qkv, u16* __restrict__ obf) {
  __shared__ __attribute__((aligned(16))) u16 VT[64 * ALP];
  __shared__ __attribute__((aligned(16))) u16 P[4][16 * ALP];
  const int tid = threadIdx.x, w = tid >> 6, lane = tid & 63;
  const int b = blockIdx.x / NHEAD, h = blockIdx.x % NHEAD;
  const u16* qb = qkv + (size_t)b * SEQ * 2304 + h * 64;
  // stage V^T: VT[n][k] = V[token k][dim n], k>=197 clamped (P=0 there anyway)
  for (int idx = tid; idx < 64 * 224; idx += 256) {
    int n = idx / 224, k = idx - n * 224;
    int kk = k < 197 ? k : 196;
    VT[n * ALP + k] = qb[(size_t)kk * 2304 + 1536 + n];
  }
  __syncthreads();
  const int lg = lane >> 4, li = lane & 15;
  u16* Pw = &P[w][0];
  for (int mt = w; mt < 13; mt += 4) {
    f32x4 z4 = {0.f, 0.f, 0.f, 0.f};
    f32x4 s[13];
    #pragma unroll
    for (int nt = 0; nt < 13; ++nt) s[nt] = z4;
    int mrow = mt * 16 + li; if (mrow > 196) mrow = 196;
    #pragma unroll
    for (int ks = 0; ks < 2; ++ks) {
      bf16x8 a = *(const bf16x8*)(qb + (size_t)mrow * 2304 + ks * 32 + lg * 8);
      #pragma unroll
      for (int nt = 0; nt < 13; ++nt) {
        int nrow = nt * 16 + li; if (nrow > 196) nrow = 196;
        bf16x8 kf = *(const bf16x8*)(qb + (size_t)nrow * 2304 + 768 + ks * 32 + lg * 8);
        s[nt] = __builtin_amdgcn_mfma_f32_16x16x32_bf16(a, kf, s[nt], 0, 0, 0);
      }
    }
    // softmax over cols (token axis), rows spread as (lg*4+r)
    float mx[4] = {-3e38f, -3e38f, -3e38f, -3e38f};
    #pragma unroll
    for (int nt = 0; nt < 13; ++nt) {
      int col = nt * 16 + li;
      #pragma unroll
      for (int r = 0; r < 4; ++r) {
        float v = (col < 197) ? s[nt][r] * 0.125f : -3e38f;
        s[nt][r] = v;
        mx[r] = fmaxf(mx[r], v);
      }
    }
    #pragma unroll
    for (int r = 0; r < 4; ++r)
      #pragma unroll
      for (int msk = 1; msk < 16; msk <<= 1)
        mx[r] = fmaxf(mx[r], __shfl_xor(mx[r], msk, 64));
    float sm[4] = {0.f, 0.f, 0.f, 0.f};
    #pragma unroll
    for (int nt = 0; nt < 13; ++nt)
      #pragma unroll
      for (int r = 0; r < 4; ++r) {
        float e = __expf(s[nt][r] - mx[r]);
        s[nt][r] = e;
        sm[r] += e;
      }
    #pragma unroll
    for (int r = 0; r < 4; ++r)
      #pragma unroll
      for (int msk = 1; msk < 16; msk <<= 1)
        sm[r] += __shfl_xor(sm[r], msk, 64);
    float inv[4];
    #pragma unroll
    for (int r = 0; r < 4; ++r) inv[r] = 1.f / sm[r];
    #pragma unroll
    for (int nt = 0; nt < 13; ++nt)
      #pragma unroll
      for (int r = 0; r < 4; ++r)
        Pw[(lg * 4 + r) * ALP + nt * 16 + li] = f2bf(s[nt][r] * inv[r]);
    for (int z = lane; z < 256; z += 64) {  // zero cols 208..223
      int rr = z >> 4, cc = 208 + (z & 15);
      Pw[rr * ALP + cc] = 0;
    }
    __threadfence_block();
    // O = P @ V  (K=224)
    f32x4 o[4];
    #pragma unroll
    for (int j = 0; j < 4; ++j) o[j] = z4;
    #pragma unroll
    for (int kt = 0; kt < 7; ++kt) {
      bf16x8 a = *(const bf16x8*)(Pw + li * ALP + kt * 32 + lg * 8);
      #pragma unroll
      for (int j = 0; j < 4; ++j) {
        bf16x8 vf = *(const bf16x8*)(VT + (j * 16 + li) * ALP + kt * 32 + lg * 8);
        o[j] = __builtin_amdgcn_mfma_f32_16x16x32_bf16(a, vf, o[j], 0, 0, 0);
      }
    }
    #pragma unroll
    for (int j = 0; j < 4; ++j)
      #pragma unroll
      for (int r = 0; r < 4; ++r) {
        int m = mt * 16 + lg * 4 + r;
        if (m < 197)
          obf[((size_t)b * SEQ + m) * DIM + h * 64 + j * 16 + li] = f2bf(o[j][r]);
      }
  }
}

// ---------------- combine residual + gate + LN3 -> bf16 ----------------
__global__ __launch_bounds__(256) void k_combine_ln(
    const float* __restrict__ tok, const float* __restrict__ ssmy,
    const float* __restrict__ attny, const float* __restrict__ wob,
    const float* __restrict__ gp, const float* __restrict__ n3w, const float* __restrict__ n3b,
    float* __restrict__ comb, u16* __restrict__ ln3bf) {
  __shared__ float red[8];
  int row = blockIdx.x, tid = threadIdx.x;
  float g = gp[0];
  long rb = (long)row * DIM;
  float c[3];
  float s = 0.f, s2 = 0.f;
  #pragma unroll
  for (int j = 0; j < 3; ++j) {
    int d = tid + j * 256;
    float a = attny[rb + d] + wob[d];
    float v = tok[rb + d] + g * ssmy[rb + d] + (1.f - g) * a;
    c[j] = v;
    comb[rb + d] = v;
    s += v;
    s2 += v * v;
  }
  #pragma unroll
  for (int m = 1; m < 64; m <<= 1) { s += __shfl_xor(s, m, 64); s2 += __shfl_xor(s2, m, 64); }
  if ((tid & 63) == 0) { red[(tid >> 6) * 2] = s; red[(tid >> 6) * 2 + 1] = s2; }
  __syncthreads();
  s = red[0] + red[2] + red[4] + red[6];
  s2 = red[1] + red[3] + red[5] + red[7];
  float mean = s * (1.f / 768.f);
  float var = s2 * (1.f / 768.f) - mean * mean;
  float rstd = rsqrtf(var + 1e-5f);
  #pragma unroll
  for (int j = 0; j < 3; ++j) {
    int d = tid + j * 256;
    float y = (c[j] - mean) * rstd * n3w[d] + n3b[d];
    ln3bf[rb + d] = f2bf(y);
  }
}

// ---------------- head: out[b,n] = feats[b,:] . head_w[n,:] + head_b[n] (fp32) ----------------
__global__ void k_head(const float* __restrict__ feats, const float* __restrict__ hw,
                       const float* __restrict__ hb, float* __restrict__ out) {
  int gid = blockIdx.x * 256 + threadIdx.x;
  if (gid >= 16 * 1000) return;
  int n = gid % 1000, b = gid / 1000;
  const float* wr = hw + (long)n * 768;
  const float* fr = feats + (long)b * 768;
  float a = hb[n];
  for (int d = 0; d < 768; d += 4) {
    f32x4 wv = *(const f32x4*)(wr + d);
    f32x4 fv = *(const f32x4*)(fr + d);
    a += wv[0] * fv[0] + wv[1] * fv[1] + wv[2] * fv[2] + wv[3] * fv[3];
  }
  out[gid] = a;
}

// ================================================================================
extern "C" void kernel_launch(void* const* d_in, const int* in_sizes, int n_in,
                              void* d_out, int out_size, void* d_ws, size_t ws_size,
                              hipStream_t stream) {
  (void)in_sizes; (void)n_in; (void)out_size;
  const float* x       = (const float*)d_in[0];
  const float* patch_w = (const float*)d_in[1];
  const float* patch_b = (const float*)d_in[2];
  const float* pos     = (const float*)d_in[3];
  const float* cls     = (const float*)d_in[4];
  const float* n1w = (const float*)d_in[5];
  const float* n1b = (const float*)d_in[6];
  const float* n2w = (const float*)d_in[7];
  const float* n2b = (const float*)d_in[8];
  const float* n3w = (const float*)d_in[9];
  const float* n3b = (const float*)d_in[10];
  const float* A_log = (const float*)d_in[11];
  const float* Dp    = (const float*)d_in[12];
  const float* xproj_w = (const float*)d_in[13];
  const float* dtw  = (const float*)d_in[14];
  const float* dtb  = (const float*)d_in[15];
  const float* conv_w = (const float*)d_in[16];
  const float* conv_b = (const float*)d_in[17];
  const float* wq = (const float*)d_in[18];
  const float* wk = (const float*)d_in[19];
  const float* wv = (const float*)d_in[20];
  const float* wo_w = (const float*)d_in[21];
  const float* wo_b = (const float*)d_in[22];
  const float* m1w = (const float*)d_in[23];
  const float* m1b = (const float*)d_in[24];
  const float* m2w = (const float*)d_in[25];
  const float* m2b = (const float*)d_in[26];
  const float* gate = (const float*)d_in[27];
  const float* fn_w = (const float*)d_in[28];
  const float* fn_b = (const float*)d_in[29];
  const float* head_w = (const float*)d_in[30];
  const float* head_b = (const float*)d_in[31];
  float* out = (float*)d_out;

  char* p = (char*)d_ws;
  auto alloc = [&](size_t bytes) {
    void* r = (void*)p;
    p += (bytes + 255) & ~(size_t)255;
    return r;
  };
  u16* wpatch = (u16*)alloc(589824ull * 2);
  u16* wxp    = (u16*)alloc(737280ull * 2);
  u16* wdt    = (u16*)alloc(589824ull * 2);
  u16* wqkv   = (u16*)alloc(21233664ull * 2);
  u16* wwo    = (u16*)alloc(7077888ull * 2);
  u16* wm1    = (u16*)alloc(28311552ull * 2);
  u16* wm2    = (u16*)alloc(28311552ull * 2);
  u16* Xp     = (u16*)alloc(2408448ull * 2);
  float* peout = (float*)alloc(2408448ull * 4);
  float* tok   = (float*)alloc(2420736ull * 4);
  float* xn    = (float*)alloc(2420736ull * 4);
  float* xcf   = (float*)alloc(2420736ull * 4);
  u16* xcbf    = (u16*)alloc(2420736ull * 2);
  float* xdbl  = (float*)alloc(252160ull * 4);
  u16* dtpad   = (u16*)alloc(201728ull * 2);
  float* Bmb   = (float*)alloc(50432ull * 4);
  float* Cmb   = (float*)alloc(50432ull * 4);
  float* dtraw = (float*)alloc(2420736ull * 4);
  float* ssmy  = (float*)alloc(2420736ull * 4);
  u16* x2bf    = (u16*)alloc(2420736ull * 2);
  u16* qkvbf   = (u16*)alloc(7262208ull * 2);
  u16* obf     = (u16*)alloc(2420736ull * 2);
  float* attny = (float*)alloc(2420736ull * 4);
  float* comb  = (float*)alloc(2420736ull * 4);
  u16* ln3bf   = (u16*)alloc(2420736ull * 2);
  u16* mlp1    = (u16*)alloc(9682944ull * 2);
  float* feats = (float*)alloc(12288ull * 4);
  if ((size_t)(p - (char*)d_ws) > ws_size) return;  // workspace too small: fail loudly

  auto cdiv = [](long a, long b) { return (int)((a + b - 1) / b); };

  // ---- weight conversion ----
  k_cvt_off4<<<cdiv(147456, 256), 256, 0, stream>>>(patch_w, wpatch, 147456, 0, 0, 147456);
  k_cvt_off4<<<cdiv(184320, 256), 256, 0, stream>>>(xproj_w, wxp, 184320, 0, 0, 184320);
  k_cvt_dtw4<<<cdiv(147456, 256), 256, 0, stream>>>(dtw, wdt);
  k_cvt_off4<<<cdiv(1769472, 256), 256, 0, stream>>>(wq, wqkv, 147456, 1769472, 0, 1769472);
  k_cvt_off4<<<cdiv(1769472, 256), 256, 0, stream>>>(wk, wqkv, 147456, 1769472, 589824, 1769472);
  k_cvt_off4<<<cdiv(1769472, 256), 256, 0, stream>>>(wv, wqkv, 147456, 1769472, 1179648, 1769472);
  k_cvt_off4<<<cdiv(1769472, 256), 256, 0, stream>>>(wo_w, wwo, 1769472, 0, 0, 1769472);
  k_cvt_off4<<<cdiv(7077888, 256), 256, 0, stream>>>(m1w, wm1, 7077888, 0, 0, 7077888);
  k_cvt_off4<<<cdiv(7077888, 256), 256, 0, stream>>>(m2w, wm2, 7077888, 0, 0, 7077888);

  // ---- patch embed ----
  k_patch_gather<<<cdiv((long)PROWS * 192, 256), 256, 0, stream>>>(x, Xp);
  {
    dim3 g(cdiv(PROWS, 128), 6);
    k_gemm<1><<<g, 256, 0, stream>>>(Xp, wpatch, peout, patch_b, nullptr,
                                     PROWS, DIM, DIM, DIM, DIM, DIM);
  }
  k_assemble<<<cdiv((long)MROWS * 192, 256), 256, 0, stream>>>(peout, pos, cls, tok);

  // ---- layers ----
  for (int lyr = 0; lyr < 12; ++lyr) {
    const float* n1w_l = n1w + lyr * DIM;  const float* n1b_l = n1b + lyr * DIM;
    const float* n2w_l = n2w + lyr * DIM;  const float* n2b_l = n2b + lyr * DIM;
    const float* n3w_l = n3w + lyr * DIM;  const float* n3b_l = n3b + lyr * DIM;
    const float* Al_l  = A_log + (size_t)lyr * DIM * 16;
    const float* Dp_l  = Dp + lyr * DIM;
    const u16*   wxp_l = wxp + (size_t)lyr * 80 * DIM;
    const u16*   wdt_l = wdt + (size_t)lyr * DIM * 64;
    const float* dtb_l = dtb + lyr * DIM;
    const float* cw_l  = conv_w + (size_t)lyr * DIM * 4;
    const float* cb_l  = conv_b + lyr * DIM;
    const u16*   wqkv_l = wqkv + (size_t)lyr * 2304 * DIM;
    const u16*   wwo_l  = wwo + (size_t)lyr * DIM * DIM;
    const float* wob_l  = wo_b + lyr * DIM;
    const u16*   wm1_l  = wm1 + (size_t)lyr * MLPD * DIM;
    const float* m1b_l  = m1b + lyr * MLPD;
    const u16*   wm2_l  = wm2 + (size_t)lyr * DIM * MLPD;
    const float* m2b_l  = m2b + lyr * DIM;
    const float* gate_l = gate + lyr;

    // SSM branch
    k_layernorm<<<MROWS, 256, 0, stream>>>(tok, DIM, n1w_l, n1b_l, xn, nullptr, DIM);
    k_conv<<<cdiv((long)MROWS * DIM, 256), 256, 0, stream>>>(xn, cw_l, cb_l, xcf, xcbf);
    {
      dim3 g(cdiv(MROWS, 128), 1);
      k_gemm<0><<<g, 256, 0, stream>>>(xcbf, wxp_l, xdbl, nullptr, nullptr,
                                       MROWS, 80, DIM, DIM, DIM, 80);
    }
    k_split<<<cdiv((long)MROWS * 96, 256), 256, 0, stream>>>(xdbl, dtpad, Bmb, Cmb);
    {
      dim3 g(cdiv(MROWS, 128), 6);
      k_gemm<0><<<g, 256, 0, stream>>>(dtpad, wdt_l, dtraw, nullptr, nullptr,
                                       MROWS, DIM, 64, 64, 64, DIM);
    }
    k_scan<<<192, 256, 0, stream>>>(dtraw, xcf, Bmb, Cmb, Al_l, dtb_l, Dp_l, ssmy);

    // attention branch
    k_layernorm<<<MROWS, 256, 0, stream>>>(tok, DIM, n2w_l, n2b_l, nullptr, x2bf, DIM);
    {
      dim3 g(cdiv(MROWS, 128), 18);
      k_gemm<3><<<g, 256, 0, stream>>>(x2bf, wqkv_l, qkvbf, nullptr, nullptr,
                                       MROWS, 2304, DIM, DIM, DIM, 2304);
    }
    k_attn<<<NB * NHEAD, 256, 0, stream>>>(qkvbf, obf);
    {
      dim3 g(cdiv(MROWS, 128), 6);
      k_gemm<0><<<g, 256, 0, stream>>>(obf, wwo_l, attny, nullptr, nullptr,
                                       MROWS, DIM, DIM, DIM, DIM, DIM);
    }

    // combine + MLP
    k_combine_ln<<<MROWS, 256, 0, stream>>>(tok, ssmy, attny, wob_l, gate_l, n3w_l, n3b_l,
                                            comb, ln3bf);
    {
      dim3 g(cdiv(MROWS, 128), 24);
      k_gemm<2><<<g, 256, 0, stream>>>(ln3bf, wm1_l, mlp1, m1b_l, nullptr,
                                       MROWS, MLPD, DIM, DIM, DIM, MLPD);
    }
    {
      dim3 g(cdiv(MROWS, 128), 6);
      k_gemm<4><<<g, 256, 0, stream>>>(mlp1, wm2_l, tok, m2b_l, comb,
                                       MROWS, DIM, MLPD, MLPD, MLPD, DIM);
    }
  }

  // ---- final LN (cls token) + head ----
  k_layernorm<<<16, 256, 0, stream>>>(tok, (long)SEQ * DIM, fn_w, fn_b, feats, nullptr, DIM);
  k_head<<<cdiv(16000, 256), 256, 0, stream>>>(feats, head_w, head_b, out);
}

// Round 3
// 5034.731 us; speedup vs baseline: 1.1800x; 1.1800x over previous
//
#include <hip/hip_runtime.h>

typedef unsigned short u16;
typedef short bf16x8 __attribute__((ext_vector_type(8)));
typedef float f32x4 __attribute__((ext_vector_type(4)));
typedef u16 u16x4 __attribute__((ext_vector_type(4)));

#define DEV __device__ __forceinline__

#define NB 16
#define SEQ 197
#define DIM 768
#define MROWS (NB * SEQ)      // 3152
#define NPATCH 196
#define PROWS (NB * NPATCH)   // 3136
#define MLPD 3072
#define NHEAD 12

DEV u16 f2bf(float f) {
  union { float f; unsigned u; } c; c.f = f;
  return (u16)((c.u + 0x7FFFu + ((c.u >> 16) & 1u)) >> 16);
}

DEV void async_ld16(const void* g, void* l) {
  __builtin_amdgcn_global_load_lds(
      (__attribute__((address_space(1))) unsigned int*)(g),
      (__attribute__((address_space(3))) unsigned int*)(l), 16, 0, 0);
}

// ---------------- weight conversion (f32 -> bf16), vectorized x4 ----------------
__global__ void k_cvt_off4(const float* __restrict__ src, u16* __restrict__ dst,
                           long npl4, long dstride, long off, long n4) {
  long i = (long)blockIdx.x * 256 + threadIdx.x;
  long st = (long)gridDim.x * 256;
  for (; i < n4; i += st) {
    long layer = i / npl4, rem = i - layer * npl4;
    f32x4 v = *(const f32x4*)(src + i * 4);
    u16x4 o;
    #pragma unroll
    for (int j = 0; j < 4; ++j) o[j] = f2bf(v[j]);
    *(u16x4*)(dst + layer * dstride + off + rem * 4) = o;
  }
}

// dtproj_w (12,768,48) -> (12,768,64) bf16, zero-padded cols 48..63
__global__ void k_cvt_dtw4(const float* __restrict__ src, u16* __restrict__ dst) {
  long i = (long)blockIdx.x * 256 + threadIdx.x;  // over 12*768*16 groups of 4
  if (i >= 12L * 768 * 16) return;
  long e = i * 4;
  long col = e & 63, row = e >> 6;
  u16x4 o;
  if (col < 48) {
    f32x4 v = *(const f32x4*)(src + row * 48 + col);
    #pragma unroll
    for (int j = 0; j < 4; ++j) o[j] = f2bf(v[j]);
  } else {
    o[0] = o[1] = o[2] = o[3] = 0;
  }
  *(u16x4*)(dst + e) = o;
}

// ---------------- patch embed ----------------
__global__ void k_patch_gather(const float* __restrict__ x, u16* __restrict__ Xp) {
  long i = (long)blockIdx.x * 256 + threadIdx.x;  // 3136*192
  if (i >= (long)PROWS * 192) return;
  int kk = (int)(i % 192) * 4;
  long m = i / 192;
  int bb = (int)(m / NPATCH), t = (int)(m % NPATCH);
  int ph = t / 14, pw = t - ph * 14;
  int c = kk >> 8, py = (kk >> 4) & 15, px = kk & 15;
  const float* sp = x + (((long)bb * 3 + c) * 224 + ph * 16 + py) * 224 + pw * 16 + px;
  f32x4 v = *(const f32x4*)sp;
  u16x4 o;
  #pragma unroll
  for (int j = 0; j < 4; ++j) o[j] = f2bf(v[j]);
  *(u16x4*)(Xp + m * DIM + kk) = o;
}

__global__ void k_assemble(const float* __restrict__ peout, const float* __restrict__ pos,
                           const float* __restrict__ cls, float* __restrict__ tok) {
  long i = (long)blockIdx.x * 256 + threadIdx.x;  // 3152*192
  if (i >= (long)MROWS * 192) return;
  int d4 = (int)(i % 192) * 4;
  long m = i / 192;
  int l = (int)(m % SEQ);
  long bb = m / SEQ;
  f32x4 v;
  if (l == 0) {
    v = *(const f32x4*)(cls + d4);
  } else {
    long pm = bb * NPATCH + (l - 1);
    f32x4 a = *(const f32x4*)(peout + pm * DIM + d4);
    f32x4 pz = *(const f32x4*)(pos + (long)(l - 1) * DIM + d4);
    v = a + pz;
  }
  *(f32x4*)(tok + m * DIM + d4) = v;
}

// ---------------- layernorm (D=768, block=256, 3 elems/thread) ----------------
__global__ __launch_bounds__(256) void k_layernorm(
    const float* __restrict__ x, long rstride,
    const float* __restrict__ w, const float* __restrict__ bb,
    float* __restrict__ outf, u16* __restrict__ outbf, long ostride) {
  __shared__ float red[8];
  int row = blockIdx.x, tid = threadIdx.x;
  const float* xr = x + (long)row * rstride;
  float v0 = xr[tid], v1 = xr[tid + 256], v2 = xr[tid + 512];
  float s = v0 + v1 + v2, s2 = v0 * v0 + v1 * v1 + v2 * v2;
  #pragma unroll
  for (int m = 1; m < 64; m <<= 1) { s += __shfl_xor(s, m, 64); s2 += __shfl_xor(s2, m, 64); }
  if ((tid & 63) == 0) { red[(tid >> 6) * 2] = s; red[(tid >> 6) * 2 + 1] = s2; }
  __syncthreads();
  s = red[0] + red[2] + red[4] + red[6];
  s2 = red[1] + red[3] + red[5] + red[7];
  float mean = s * (1.f / 768.f);
  float var = s2 * (1.f / 768.f) - mean * mean;
  float rstd = rsqrtf(var + 1e-5f);
  float* of = outf ? outf + (long)row * ostride : nullptr;
  u16* ob = outbf ? outbf + (long)row * ostride : nullptr;
  int d = tid;
  #pragma unroll
  for (int j = 0; j < 3; ++j, d += 256) {
    float val = (j == 0) ? v0 : ((j == 1) ? v1 : v2);
    float y = (val - mean) * rstd * w[d] + bb[d];
    if (of) of[d] = y;
    if (ob) ob[d] = f2bf(y);
  }
}

// ---------------- causal depthwise conv (K=4, left pad 3) ----------------
__global__ void k_conv(const float* __restrict__ xn, const float* __restrict__ cw,
                       const float* __restrict__ cb, float* __restrict__ xc,
                       u16* __restrict__ xcbf) {
  long gid = (long)blockIdx.x * 256 + threadIdx.x;
  if (gid >= (long)MROWS * DIM) return;
  int d = (int)(gid % DIM);
  long m = gid / DIM;
  int l = (int)(m % SEQ);
  long b = m / SEQ;
  const float* w4 = cw + (long)d * 4;
  float a = cb[d];
  #pragma unroll
  for (int k = 0; k < 4; ++k) {
    int ls = l - 3 + k;
    if (ls >= 0) a += w4[k] * xn[(b * SEQ + ls) * DIM + d];
  }
  xc[gid] = a;
  xcbf[gid] = f2bf(a);
}

// ---------------- split x_dbl (3152x80) -> dtpad bf16 (x64), Bm, Cm f32 (x16) ----------------
__global__ void k_split(const float* __restrict__ xdbl, u16* __restrict__ dtpad,
                        float* __restrict__ Bm, float* __restrict__ Cm) {
  long gid = (long)blockIdx.x * 256 + threadIdx.x;
  if (gid >= (long)MROWS * 96) return;
  int j = (int)(gid % 96);
  long m = gid / 96;
  const float* xr = xdbl + m * 80;
  if (j < 64) dtpad[m * 64 + j] = (j < 48) ? f2bf(xr[j]) : (u16)0;
  else if (j < 80) Bm[m * 16 + (j - 64)] = xr[j - 16];
  else Cm[m * 16 + (j - 80)] = xr[j - 16];
}

// ---------------- selective scan v2: thread = (b, d, state n); 16-way state split ----------------
// dt_ already has softplus(dtraw + dtb) applied (GEMM MODE 5 epilogue).
// Prefetches l+1 operands into registers to hide L2 latency under compute.
__global__ __launch_bounds__(256) void k_scan(
    const float* __restrict__ dt_, const float* __restrict__ xc,
    const float* __restrict__ Bm, const float* __restrict__ Cm,
    const float* __restrict__ Alog, const float* __restrict__ Dpr,
    float* __restrict__ ssmy) {
  int gid = blockIdx.x * 256 + threadIdx.x;  // 16*768*16 = 196608
  int n = gid & 15;
  int rest = gid >> 4;
  int d = rest % DIM;
  int b = rest / DIM;
  float a = -__expf(Alog[d * 16 + n]);
  float Dv = Dpr[d];
  float h = 0.f;
  long base = (long)b * SEQ * DIM + d;   // dt/xc stride DIM per l
  long cbase = (long)b * SEQ * 16 + n;   // B/C stride 16 per l
  // current-iteration operands
  float dt = dt_[base], xcv = xc[base];
  float Bv = Bm[cbase], Cv = Cm[cbase];
  #pragma unroll 2
  for (int l = 0; l < SEQ; ++l) {
    // prefetch next iteration (unconditional; last reads spill into adjacent ws region, unused)
    long nb = base + (long)(l + 1) * DIM;
    long nc = cbase + (long)(l + 1) * 16;
    float dt_n = dt_[nb], xc_n = xc[nb];
    float B_n = Bm[nc], C_n = Cm[nc];
    float dtx = dt * xcv;
    h = __expf(dt * a) * h + dtx * Bv;
    float y = h * Cv;
    y += __shfl_xor(y, 1, 64);
    y += __shfl_xor(y, 2, 64);
    y += __shfl_xor(y, 4, 64);
    y += __shfl_xor(y, 8, 64);
    if (n == 0) ssmy[base + (long)l * DIM] = y + xcv * Dv;
    dt = dt_n; xcv = xc_n; Bv = B_n; Cv = C_n;
  }
}

// ---------------- GEMM: C[M,N] = A[M,K](bf16) @ W[N,K]^T(bf16), 128x128 tile ----------------
// MODE 0: f32 C=acc; 1: f32 C=acc+bias; 2: bf16 C=gelu(acc+bias); 3: bf16 C=acc;
// 4: f32 C=acc+bias+res; 5: f32 C=softplus(acc+bias)
template <int MODE>
__global__ __launch_bounds__(256) void k_gemm(
    const u16* __restrict__ A, const u16* __restrict__ Bw, void* __restrict__ Cout,
    const float* __restrict__ bias, const float* __restrict__ res,
    int M, int N, int K, int lda, int ldb, int ldc) {
  __shared__ __attribute__((aligned(16))) u16 lA[128 * 32];
  __shared__ __attribute__((aligned(16))) u16 lB[128 * 32];
  const int tid = threadIdx.x;
  const int w = tid >> 6, lane = tid & 63;
  const int m0 = blockIdx.x * 128, n0 = blockIdx.y * 128;
  const int wr = (w >> 1) * 64, wc = (w & 1) * 64;
  const int lg = lane >> 4, li = lane & 15;

  f32x4 z4 = {0.f, 0.f, 0.f, 0.f};
  f32x4 acc[4][4];
  #pragma unroll
  for (int i = 0; i < 4; ++i)
    #pragma unroll
    for (int j = 0; j < 4; ++j) acc[i][j] = z4;

  const int srow = w * 16 + (lane >> 2);   // staging row (+ r*64)
  const int skcol = (lane & 3) * 8;        // staging k offset (elems)

  for (int k0 = 0; k0 < K; k0 += 32) {
    #pragma unroll
    for (int r = 0; r < 2; ++r) {
      int ra = m0 + srow + r * 64; if (ra > M - 1) ra = M - 1;
      async_ld16(A + (size_t)ra * lda + k0 + skcol, lA + (r * 4 + w) * 512);
      int rb = n0 + srow + r * 64; if (rb > N - 1) rb = N - 1;
      async_ld16(Bw + (size_t)rb * ldb + k0 + skcol, lB + (r * 4 + w) * 512);
    }
    __syncthreads();
    bf16x8 af[4], bfr[4];
    #pragma unroll
    for (int i = 0; i < 4; ++i)
      af[i] = *(const bf16x8*)(lA + (wr + i * 16 + li) * 32 + lg * 8);
    #pragma unroll
    for (int j = 0; j < 4; ++j)
      bfr[j] = *(const bf16x8*)(lB + (wc + j * 16 + li) * 32 + lg * 8);
    #pragma unroll
    for (int i = 0; i < 4; ++i)
      #pragma unroll
      for (int j = 0; j < 4; ++j)
        acc[i][j] = __builtin_amdgcn_mfma_f32_16x16x32_bf16(af[i], bfr[j], acc[i][j], 0, 0, 0);
    __syncthreads();
  }

  float* Cf = (float*)Cout;
  u16* Cb = (u16*)Cout;
  #pragma unroll
  for (int i = 0; i < 4; ++i) {
    #pragma unroll
    for (int j = 0; j < 4; ++j) {
      int ncol = n0 + wc + j * 16 + li;
      if (ncol >= N) continue;
      #pragma unroll
      for (int r = 0; r < 4; ++r) {
        int m = m0 + wr + i * 16 + lg * 4 + r;
        if (m >= M) continue;
        float v = acc[i][j][r];
        size_t idx = (size_t)m * ldc + ncol;
        if constexpr (MODE == 0) {
          Cf[idx] = v;
        } else if constexpr (MODE == 1) {
          Cf[idx] = v + bias[ncol];
        } else if constexpr (MODE == 2) {
          float t = v + bias[ncol];
          Cb[idx] = f2bf(0.5f * t * (1.f + erff(t * 0.70710678118f)));
        } else if constexpr (MODE == 3) {
          Cb[idx] = f2bf(v);
        } else if constexpr (MODE == 4) {
          Cf[idx] = v + bias[ncol] + res[idx];
        } else {  // 5: softplus(acc + bias)
          float t = v + bias[ncol];
          Cf[idx] = t > 20.f ? t : log1pf(__expf(t));
        }
      }
    }
  }
}

// ---------------- fused attention per (b,h): qkv bf16 (M x 2304) -> o bf16 (M x 768) ----------------
#define ALP 232  // padded k-stride for VT / P (2-way-ish LDS banks)
__global__ __launch_bounds__(256) void k_attn(const u16* __restrict__ qkv, u16* __restrict__ obf) {
  __shared__ __attribute__((aligned(16))) u16 VT[64 * ALP];
  __shared__ __attribute__((aligned(16))) u16 P[4][16 * ALP];
  const int tid = threadIdx.x, w = tid >> 6, lane = tid & 63;
  const int b = blockIdx.x / NHEAD, h = blockIdx.x % NHEAD;
  const u16* qb = qkv + (size_t)b * SEQ * 2304 + h * 64;
  // stage V^T: VT[n][k] = V[token k][dim n], k>=197 clamped (P=0 there anyway)
  for (int idx = tid; idx < 64 * 224; idx += 256) {
    int n = idx / 224, k = idx - n * 224;
    int kk = k < 197 ? k : 196;
    VT[n * ALP + k] = qb[(size_t)kk * 2304 + 1536 + n];
  }
  __syncthreads();
  const int lg = lane >> 4, li = lane & 15;
  u16* Pw = &P[w][0];
  for (int mt = w; mt < 13; mt += 4) {
    f32x4 z4 = {0.f, 0.f, 0.f, 0.f};
    f32x4 s[13];
    #pragma unroll
    for (int nt = 0; nt < 13; ++nt) s[nt] = z4;
    int mrow = mt * 16 + li; if (mrow > 196) mrow = 196;
    #pragma unroll
    for (int ks = 0; ks < 2; ++ks) {
      bf16x8 a = *(const bf16x8*)(qb + (size_t)mrow * 2304 + ks * 32 + lg * 8);
      #pragma unroll
      for (int nt = 0; nt < 13; ++nt) {
        int nrow = nt * 16 + li; if (nrow > 196) nrow = 196;
        bf16x8 kf = *(const bf16x8*)(qb + (size_t)nrow * 2304 + 768 + ks * 32 + lg * 8);
        s[nt] = __builtin_amdgcn_mfma_f32_16x16x32_bf16(a, kf, s[nt], 0, 0, 0);
      }
    }
    // softmax over cols (token axis), rows spread as (lg*4+r)
    float mx[4] = {-3e38f, -3e38f, -3e38f, -3e38f};
    #pragma unroll
    for (int nt = 0; nt < 13; ++nt) {
      int col = nt * 16 + li;
      #pragma unroll
      for (int r = 0; r < 4; ++r) {
        float v = (col < 197) ? s[nt][r] * 0.125f : -3e38f;
        s[nt][r] = v;
        mx[r] = fmaxf(mx[r], v);
      }
    }
    #pragma unroll
    for (int r = 0; r < 4; ++r)
      #pragma unroll
      for (int msk = 1; msk < 16; msk <<= 1)
        mx[r] = fmaxf(mx[r], __shfl_xor(mx[r], msk, 64));
    float sm[4] = {0.f, 0.f, 0.f, 0.f};
    #pragma unroll
    for (int nt = 0; nt < 13; ++nt)
      #pragma unroll
      for (int r = 0; r < 4; ++r) {
        float e = __expf(s[nt][r] - mx[r]);
        s[nt][r] = e;
        sm[r] += e;
      }
    #pragma unroll
    for (int r = 0; r < 4; ++r)
      #pragma unroll
      for (int msk = 1; msk < 16; msk <<= 1)
        sm[r] += __shfl_xor(sm[r], msk, 64);
    float inv[4];
    #pragma unroll
    for (int r = 0; r < 4; ++r) inv[r] = 1.f / sm[r];
    #pragma unroll
    for (int nt = 0; nt < 13; ++nt)
      #pragma unroll
      for (int r = 0; r < 4; ++r)
        Pw[(lg * 4 + r) * ALP + nt * 16 + li] = f2bf(s[nt][r] * inv[r]);
    for (int z = lane; z < 256; z += 64) {  // zero cols 208..223
      int rr = z >> 4, cc = 208 + (z & 15);
      Pw[rr * ALP + cc] = 0;
    }
    __threadfence_block();
    // O = P @ V  (K=224)
    f32x4 o[4];
    #pragma unroll
    for (int j = 0; j < 4; ++j) o[j] = z4;
    #pragma unroll
    for (int kt = 0; kt < 7; ++kt) {
      bf16x8 a = *(const bf16x8*)(Pw + li * ALP + kt * 32 + lg * 8);
      #pragma unroll
      for (int j = 0; j < 4; ++j) {
        bf16x8 vf = *(const bf16x8*)(VT + (j * 16 + li) * ALP + kt * 32 + lg * 8);
        o[j] = __builtin_amdgcn_mfma_f32_16x16x32_bf16(a, vf, o[j], 0, 0, 0);
      }
    }
    #pragma unroll
    for (int j = 0; j < 4; ++j)
      #pragma unroll
      for (int r = 0; r < 4; ++r) {
        int m = mt * 16 + lg * 4 + r;
        if (m < 197)
          obf[((size_t)b * SEQ + m) * DIM + h * 64 + j * 16 + li] = f2bf(o[j][r]);
      }
  }
}

// ---------------- combine residual + gate + LN3 -> bf16 ----------------
__global__ __launch_bounds__(256) void k_combine_ln(
    const float* __restrict__ tok, const float* __restrict__ ssmy,
    const float* __restrict__ attny, const float* __restrict__ wob,
    const float* __restrict__ gp, const float* __restrict__ n3w, const float* __restrict__ n3b,
    float* __restrict__ comb, u16* __restrict__ ln3bf) {
  __shared__ float red[8];
  int row = blockIdx.x, tid = threadIdx.x;
  float g = gp[0];
  long rb = (long)row * DIM;
  float c[3];
  float s = 0.f, s2 = 0.f;
  #pragma unroll
  for (int j = 0; j < 3; ++j) {
    int d = tid + j * 256;
    float a = attny[rb + d] + wob[d];
    float v = tok[rb + d] + g * ssmy[rb + d] + (1.f - g) * a;
    c[j] = v;
    comb[rb + d] = v;
    s += v;
    s2 += v * v;
  }
  #pragma unroll
  for (int m = 1; m < 64; m <<= 1) { s += __shfl_xor(s, m, 64); s2 += __shfl_xor(s2, m, 64); }
  if ((tid & 63) == 0) { red[(tid >> 6) * 2] = s; red[(tid >> 6) * 2 + 1] = s2; }
  __syncthreads();
  s = red[0] + red[2] + red[4] + red[6];
  s2 = red[1] + red[3] + red[5] + red[7];
  float mean = s * (1.f / 768.f);
  float var = s2 * (1.f / 768.f) - mean * mean;
  float rstd = rsqrtf(var + 1e-5f);
  #pragma unroll
  for (int j = 0; j < 3; ++j) {
    int d = tid + j * 256;
    float y = (c[j] - mean) * rstd * n3w[d] + n3b[d];
    ln3bf[rb + d] = f2bf(y);
  }
}

// ---------------- head: out[b,n] = feats[b,:] . head_w[n,:] + head_b[n] (fp32) ----------------
__global__ void k_head(const float* __restrict__ feats, const float* __restrict__ hw,
                       const float* __restrict__ hb, float* __restrict__ out) {
  int gid = blockIdx.x * 256 + threadIdx.x;
  if (gid >= 16 * 1000) return;
  int n = gid % 1000, b = gid / 1000;
  const float* wr = hw + (long)n * 768;
  const float* fr = feats + (long)b * 768;
  float a = hb[n];
  for (int d = 0; d < 768; d += 4) {
    f32x4 wv = *(const f32x4*)(wr + d);
    f32x4 fv = *(const f32x4*)(fr + d);
    a += wv[0] * fv[0] + wv[1] * fv[1] + wv[2] * fv[2] + wv[3] * fv[3];
  }
  out[gid] = a;
}

// ================================================================================
extern "C" void kernel_launch(void* const* d_in, const int* in_sizes, int n_in,
                              void* d_out, int out_size, void* d_ws, size_t ws_size,
                              hipStream_t stream) {
  (void)in_sizes; (void)n_in; (void)out_size;
  const float* x       = (const float*)d_in[0];
  const float* patch_w = (const float*)d_in[1];
  const float* patch_b = (const float*)d_in[2];
  const float* pos     = (const float*)d_in[3];
  const float* cls     = (const float*)d_in[4];
  const float* n1w = (const float*)d_in[5];
  const float* n1b = (const float*)d_in[6];
  const float* n2w = (const float*)d_in[7];
  const float* n2b = (const float*)d_in[8];
  const float* n3w = (const float*)d_in[9];
  const float* n3b = (const float*)d_in[10];
  const float* A_log = (const float*)d_in[11];
  const float* Dp    = (const float*)d_in[12];
  const float* xproj_w = (const float*)d_in[13];
  const float* dtw  = (const float*)d_in[14];
  const float* dtb  = (const float*)d_in[15];
  const float* conv_w = (const float*)d_in[16];
  const float* conv_b = (const float*)d_in[17];
  const float* wq = (const float*)d_in[18];
  const float* wk = (const float*)d_in[19];
  const float* wv = (const float*)d_in[20];
  const float* wo_w = (const float*)d_in[21];
  const float* wo_b = (const float*)d_in[22];
  const float* m1w = (const float*)d_in[23];
  const float* m1b = (const float*)d_in[24];
  const float* m2w = (const float*)d_in[25];
  const float* m2b = (const float*)d_in[26];
  const float* gate = (const float*)d_in[27];
  const float* fn_w = (const float*)d_in[28];
  const float* fn_b = (const float*)d_in[29];
  const float* head_w = (const float*)d_in[30];
  const float* head_b = (const float*)d_in[31];
  float* out = (float*)d_out;

  char* p = (char*)d_ws;
  auto alloc = [&](size_t bytes) {
    void* r = (void*)p;
    p += (bytes + 255) & ~(size_t)255;
    return r;
  };
  u16* wpatch = (u16*)alloc(589824ull * 2);
  u16* wxp    = (u16*)alloc(737280ull * 2);
  u16* wdt    = (u16*)alloc(589824ull * 2);
  u16* wqkv   = (u16*)alloc(21233664ull * 2);
  u16* wwo    = (u16*)alloc(7077888ull * 2);
  u16* wm1    = (u16*)alloc(28311552ull * 2);
  u16* wm2    = (u16*)alloc(28311552ull * 2);
  u16* Xp     = (u16*)alloc(2408448ull * 2);
  float* peout = (float*)alloc(2408448ull * 4);
  float* tok   = (float*)alloc(2420736ull * 4);
  float* xn    = (float*)alloc(2420736ull * 4);
  // NOTE: region order matters for the scan's one-row prefetch overrun:
  // Bmb -> Cmb -> dtraw -> ssmy and xcf -> xcbf keep overruns inside d_ws.
  float* xcf   = (float*)alloc(2420736ull * 4);
  u16* xcbf    = (u16*)alloc(2420736ull * 2);
  float* xdbl  = (float*)alloc(252160ull * 4);
  u16* dtpad   = (u16*)alloc(201728ull * 2);
  float* Bmb   = (float*)alloc(50432ull * 4);
  float* Cmb   = (float*)alloc(50432ull * 4);
  float* dtraw = (float*)alloc(2420736ull * 4);
  float* ssmy  = (float*)alloc(2420736ull * 4);
  u16* x2bf    = (u16*)alloc(2420736ull * 2);
  u16* qkvbf   = (u16*)alloc(7262208ull * 2);
  u16* obf     = (u16*)alloc(2420736ull * 2);
  float* attny = (float*)alloc(2420736ull * 4);
  float* comb  = (float*)alloc(2420736ull * 4);
  u16* ln3bf   = (u16*)alloc(2420736ull * 2);
  u16* mlp1    = (u16*)alloc(9682944ull * 2);
  float* feats = (float*)alloc(12288ull * 4);
  if ((size_t)(p - (char*)d_ws) > ws_size) return;  // workspace too small: fail loudly

  auto cdiv = [](long a, long b) { return (int)((a + b - 1) / b); };

  // ---- weight conversion ----
  k_cvt_off4<<<cdiv(147456, 256), 256, 0, stream>>>(patch_w, wpatch, 147456, 0, 0, 147456);
  k_cvt_off4<<<cdiv(184320, 256), 256, 0, stream>>>(xproj_w, wxp, 184320, 0, 0, 184320);
  k_cvt_dtw4<<<cdiv(147456, 256), 256, 0, stream>>>(dtw, wdt);
  k_cvt_off4<<<cdiv(1769472, 256), 256, 0, stream>>>(wq, wqkv, 147456, 1769472, 0, 1769472);
  k_cvt_off4<<<cdiv(1769472, 256), 256, 0, stream>>>(wk, wqkv, 147456, 1769472, 589824, 1769472);
  k_cvt_off4<<<cdiv(1769472, 256), 256, 0, stream>>>(wv, wqkv, 147456, 1769472, 1179648, 1769472);
  k_cvt_off4<<<cdiv(1769472, 256), 256, 0, stream>>>(wo_w, wwo, 1769472, 0, 0, 1769472);
  k_cvt_off4<<<cdiv(7077888, 256), 256, 0, stream>>>(m1w, wm1, 7077888, 0, 0, 7077888);
  k_cvt_off4<<<cdiv(7077888, 256), 256, 0, stream>>>(m2w, wm2, 7077888, 0, 0, 7077888);

  // ---- patch embed ----
  k_patch_gather<<<cdiv((long)PROWS * 192, 256), 256, 0, stream>>>(x, Xp);
  {
    dim3 g(cdiv(PROWS, 128), 6);
    k_gemm<1><<<g, 256, 0, stream>>>(Xp, wpatch, peout, patch_b, nullptr,
                                     PROWS, DIM, DIM, DIM, DIM, DIM);
  }
  k_assemble<<<cdiv((long)MROWS * 192, 256), 256, 0, stream>>>(peout, pos, cls, tok);

  // ---- layers ----
  for (int lyr = 0; lyr < 12; ++lyr) {
    const float* n1w_l = n1w + lyr * DIM;  const float* n1b_l = n1b + lyr * DIM;
    const float* n2w_l = n2w + lyr * DIM;  const float* n2b_l = n2b + lyr * DIM;
    const float* n3w_l = n3w + lyr * DIM;  const float* n3b_l = n3b + lyr * DIM;
    const float* Al_l  = A_log + (size_t)lyr * DIM * 16;
    const float* Dp_l  = Dp + lyr * DIM;
    const u16*   wxp_l = wxp + (size_t)lyr * 80 * DIM;
    const u16*   wdt_l = wdt + (size_t)lyr * DIM * 64;
    const float* dtb_l = dtb + lyr * DIM;
    const float* cw_l  = conv_w + (size_t)lyr * DIM * 4;
    const float* cb_l  = conv_b + lyr * DIM;
    const u16*   wqkv_l = wqkv + (size_t)lyr * 2304 * DIM;
    const u16*   wwo_l  = wwo + (size_t)lyr * DIM * DIM;
    const float* wob_l  = wo_b + lyr * DIM;
    const u16*   wm1_l  = wm1 + (size_t)lyr * MLPD * DIM;
    const float* m1b_l  = m1b + lyr * MLPD;
    const u16*   wm2_l  = wm2 + (size_t)lyr * DIM * MLPD;
    const float* m2b_l  = m2b + lyr * DIM;
    const float* gate_l = gate + lyr;

    // SSM branch
    k_layernorm<<<MROWS, 256, 0, stream>>>(tok, DIM, n1w_l, n1b_l, xn, nullptr, DIM);
    k_conv<<<cdiv((long)MROWS * DIM, 256), 256, 0, stream>>>(xn, cw_l, cb_l, xcf, xcbf);
    {
      dim3 g(cdiv(MROWS, 128), 1);
      k_gemm<0><<<g, 256, 0, stream>>>(xcbf, wxp_l, xdbl, nullptr, nullptr,
                                       MROWS, 80, DIM, DIM, DIM, 80);
    }
    k_split<<<cdiv((long)MROWS * 96, 256), 256, 0, stream>>>(xdbl, dtpad, Bmb, Cmb);
    {
      dim3 g(cdiv(MROWS, 128), 6);
      k_gemm<5><<<g, 256, 0, stream>>>(dtpad, wdt_l, dtraw, dtb_l, nullptr,
                                       MROWS, DIM, 64, 64, 64, DIM);
    }
    k_scan<<<768, 256, 0, stream>>>(dtraw, xcf, Bmb, Cmb, Al_l, Dp_l, ssmy);

    // attention branch
    k_layernorm<<<MROWS, 256, 0, stream>>>(tok, DIM, n2w_l, n2b_l, nullptr, x2bf, DIM);
    {
      dim3 g(cdiv(MROWS, 128), 18);
      k_gemm<3><<<g, 256, 0, stream>>>(x2bf, wqkv_l, qkvbf, nullptr, nullptr,
                                       MROWS, 2304, DIM, DIM, DIM, 2304);
    }
    k_attn<<<NB * NHEAD, 256, 0, stream>>>(qkvbf, obf);
    {
      dim3 g(cdiv(MROWS, 128), 6);
      k_gemm<0><<<g, 256, 0, stream>>>(obf, wwo_l, attny, nullptr, nullptr,
                                       MROWS, DIM, DIM, DIM, DIM, DIM);
    }

    // combine + MLP
    k_combine_ln<<<MROWS, 256, 0, stream>>>(tok, ssmy, attny, wob_l, gate_l, n3w_l, n3b_l,
                                            comb, ln3bf);
    {
      dim3 g(cdiv(MROWS, 128), 24);
      k_gemm<2><<<g, 256, 0, stream>>>(ln3bf, wm1_l, mlp1, m1b_l, nullptr,
                                       MROWS, MLPD, DIM, DIM, DIM, MLPD);
    }
    {
      dim3 g(cdiv(MROWS, 128), 6);
      k_gemm<4><<<g, 256, 0, stream>>>(mlp1, wm2_l, tok, m2b_l, comb,
                                       MROWS, DIM, MLPD, MLPD, MLPD, DIM);
    }
  }

  // ---- final LN (cls token) + head ----
  k_layernorm<<<16, 256, 0, stream>>>(tok, (long)SEQ * DIM, fn_w, fn_b, feats, nullptr, DIM);
  k_head<<<cdiv(16000, 256), 256, 0, stream>>>(feats, head_w, head_b, out);
}